// Round 1
// baseline (1028.464 us; speedup 1.0000x reference)
//
#include <hip/hip_runtime.h>

// FixedKAN: 2-layer Chebyshev KAN, fp32.
//   layer(x) = cheb(x @ w^T + b, coeffs) @ cW + cb
// B=16384, dims 1024 -> 1024 -> 256, D=7 (8 coeffs).
//
// Round 0: fp32 LDS-tiled SGEMM (128x128x16 tile, 256 thr, 8x8 microtile),
// fused bias+Chebyshev epilogue on the alpha GEMMs. No fp32 MFMA on CDNA4,
// so this is vector-FMA bound (~157 TF peak).

constexpr int MT = 128;   // M tile
constexpr int NT = 128;   // N tile
constexpr int KT = 16;    // K tile
constexpr int LDP = 132;  // padded LDS row stride (floats) - breaks bank conflicts

// CHEB: apply bias + Chebyshev recurrence epilogue (alpha GEMMs)
// B_NK: W stored [N,K] row-major (projection w) vs [K,N] (combine cW)
template<bool CHEB, bool B_NK>
__global__ __launch_bounds__(256)
void kan_gemm(const float* __restrict__ A,
              const float* __restrict__ W,
              const float* __restrict__ bias,
              const float* __restrict__ coeffs,
              float* __restrict__ C,
              int M, int N, int K)
{
    __shared__ float As[KT][LDP];
    __shared__ float Bs[KT][LDP];

    const int tid = threadIdx.x;
    const int bm  = blockIdx.y;
    const int bn  = blockIdx.x;
    const int tx  = tid & 15;
    const int ty  = tid >> 4;
    const int m0  = ty * 8;
    const int n0  = tx * 8;

    float acc[8][8];
#pragma unroll
    for (int i = 0; i < 8; ++i)
#pragma unroll
        for (int j = 0; j < 8; ++j) acc[i][j] = 0.f;

    const float* Ab = A + (size_t)(bm * MT) * K;

    for (int kt = 0; kt < K; kt += KT) {
        // ---- stage A tile: 128 rows x 16 cols, transposed into As[k][m]
#pragma unroll
        for (int l = 0; l < 2; ++l) {
            const int q = tid + l * 256;      // 0..511 float4-chunks
            const int r = q >> 2;             // row 0..127
            const int c = (q & 3) * 4;        // col 0,4,8,12
            const float4 v = *(const float4*)(Ab + (size_t)r * K + kt + c);
            As[c + 0][r] = v.x;
            As[c + 1][r] = v.y;
            As[c + 2][r] = v.z;
            As[c + 3][r] = v.w;
        }
        // ---- stage B tile into Bs[k][n]
        if (B_NK) {
            // W is [N,K] row-major: same pattern as A
            const float* Wb = W + (size_t)(bn * NT) * K;
#pragma unroll
            for (int l = 0; l < 2; ++l) {
                const int q = tid + l * 256;
                const int r = q >> 2;             // n 0..127
                const int c = (q & 3) * 4;        // k 0,4,8,12
                const float4 v = *(const float4*)(Wb + (size_t)r * K + kt + c);
                Bs[c + 0][r] = v.x;
                Bs[c + 1][r] = v.y;
                Bs[c + 2][r] = v.z;
                Bs[c + 3][r] = v.w;
            }
        } else {
            // W is [K,N] row-major: 16 rows x 128 cols, direct copy
            const float* Wb = W + (size_t)kt * N + bn * NT;
#pragma unroll
            for (int l = 0; l < 2; ++l) {
                const int q = tid + l * 256;
                const int r = q >> 5;             // k 0..15
                const int c = (q & 31) * 4;       // n 0..124
                const float4 v = *(const float4*)(Wb + (size_t)r * N + c);
                *(float4*)&Bs[r][c] = v;
            }
        }
        __syncthreads();

#pragma unroll
        for (int k = 0; k < KT; ++k) {
            const float4 a0 = *(const float4*)&As[k][m0];
            const float4 a1 = *(const float4*)&As[k][m0 + 4];
            const float4 b0 = *(const float4*)&Bs[k][n0];
            const float4 b1 = *(const float4*)&Bs[k][n0 + 4];
            const float a[8] = {a0.x, a0.y, a0.z, a0.w, a1.x, a1.y, a1.z, a1.w};
            const float b[8] = {b0.x, b0.y, b0.z, b0.w, b1.x, b1.y, b1.z, b1.w};
#pragma unroll
            for (int i = 0; i < 8; ++i)
#pragma unroll
                for (int j = 0; j < 8; ++j)
                    acc[i][j] = fmaf(a[i], b[j], acc[i][j]);
        }
        __syncthreads();
    }

    // ---- epilogue: bias (+ Chebyshev), store. Two 4-column halves to keep
    // coefficient buffering at 4x8 regs.
    const int gm0 = bm * MT + m0;
    const int gn0 = bn * NT + n0;

#pragma unroll
    for (int half = 0; half < 2; ++half) {
        const int nbase = gn0 + half * 4;
        float bia[4];
#pragma unroll
        for (int j = 0; j < 4; ++j) bia[j] = bias[nbase + j];

        float cf[4][8];
        if (CHEB) {
#pragma unroll
            for (int j = 0; j < 4; ++j) {
                const float4 u0 = *(const float4*)(coeffs + (size_t)(nbase + j) * 8);
                const float4 u1 = *(const float4*)(coeffs + (size_t)(nbase + j) * 8 + 4);
                cf[j][0] = u0.x; cf[j][1] = u0.y; cf[j][2] = u0.z; cf[j][3] = u0.w;
                cf[j][4] = u1.x; cf[j][5] = u1.y; cf[j][6] = u1.z; cf[j][7] = u1.w;
            }
        }

#pragma unroll
        for (int i = 0; i < 8; ++i) {
            float out[4];
#pragma unroll
            for (int j = 0; j < 4; ++j) {
                const float alpha = acc[i][half * 4 + j] + bia[j];
                float v;
                if (CHEB) {
                    // T0=1, T1=alpha; acc = c0 + c1*a; T_d = 2a*T_{d-1} - T_{d-2}
                    float tm2 = 1.f;
                    float tm1 = alpha;
                    v = fmaf(cf[j][1], alpha, cf[j][0]);
#pragma unroll
                    for (int d = 2; d < 8; ++d) {
                        const float t = 2.f * alpha * tm1 - tm2;
                        v = fmaf(cf[j][d], t, v);
                        tm2 = tm1;
                        tm1 = t;
                    }
                } else {
                    v = alpha;
                }
                out[j] = v;
            }
            float* Cp = C + (size_t)(gm0 + i) * N + nbase;
            *(float4*)Cp = make_float4(out[0], out[1], out[2], out[3]);
        }
    }
}

extern "C" void kernel_launch(void* const* d_in, const int* in_sizes, int n_in,
                              void* d_out, int out_size, void* d_ws, size_t ws_size,
                              hipStream_t stream) {
    const float* x       = (const float*)d_in[0];
    const float* w1      = (const float*)d_in[1];
    const float* b1      = (const float*)d_in[2];
    const float* coeffs1 = (const float*)d_in[3];
    const float* cW1     = (const float*)d_in[4];
    const float* cb1     = (const float*)d_in[5];
    const float* w2      = (const float*)d_in[6];
    const float* b2      = (const float*)d_in[7];
    const float* coeffs2 = (const float*)d_in[8];
    const float* cW2     = (const float*)d_in[9];
    const float* cb2     = (const float*)d_in[10];

    constexpr int B  = 16384;
    constexpr int D0 = 1024;   // in
    constexpr int D1 = 1024;   // hidden
    constexpr int D2 = 256;    // out

    float* buf1 = (float*)d_ws;                      // [B, D1] (later reused [B, D2])
    float* buf2 = buf1 + (size_t)B * D1;             // [B, D1]
    float* outp = (float*)d_out;                     // [B, D2]

    const dim3 blk(256);

    // layer 1: alpha1 = x @ w1^T + b1 ; cheb -> buf1
    kan_gemm<true, true><<<dim3(D1 / NT, B / MT), blk, 0, stream>>>(
        x, w1, b1, coeffs1, buf1, B, D1, D0);
    // h = buf1 @ cW1 + cb1 -> buf2
    kan_gemm<false, false><<<dim3(D1 / NT, B / MT), blk, 0, stream>>>(
        buf1, cW1, cb1, nullptr, buf2, B, D1, D1);
    // layer 2: alpha2 = h @ w2^T + b2 ; cheb -> buf1 (first B*D2 floats)
    kan_gemm<true, true><<<dim3(D2 / NT, B / MT), blk, 0, stream>>>(
        buf2, w2, b2, coeffs2, buf1, B, D2, D1);
    // out = buf1 @ cW2 + cb2 -> d_out
    kan_gemm<false, false><<<dim3(D2 / NT, B / MT), blk, 0, stream>>>(
        buf1, cW2, cb2, nullptr, outp, B, D2, D2);
}

// Round 2
// 496.552 us; speedup vs baseline: 2.0712x; 2.0712x over previous
//
#include <hip/hip_runtime.h>

// FixedKAN round 2: split-bf16 (Markidis 3-product) MFMA pipeline.
//   n1 = cheb1(x @ w1^T + b1)                      [16384,1024]
//   alpha2 = n1 @ M2T^T + bias2eff,  M2T[n][j] = dot(w2[n,:], cW1[j,:])
//   p = cheb2(alpha2)                              [16384,256]
//   out = p @ cW2 + cb2                            [16384,256]
// Each GEMM: A = Ah+Al (bf16), B = Bh+Bl (bf16), acc += AhBh + AhBl + AlBh (f32 MFMA).

typedef __attribute__((ext_vector_type(8))) short short8;
typedef __attribute__((ext_vector_type(4))) float f32x4;

__device__ __forceinline__ void split2(float f, unsigned short& h, unsigned short& l) {
    const unsigned u = __float_as_uint(f);
    h = (unsigned short)(u >> 16);                       // truncate hi
    const float hf = __uint_as_float(u & 0xFFFF0000u);
    l = (unsigned short)(__float_as_uint(f - hf) >> 16); // truncate residual
}

// ---------------------------------------------------------------- prep kernels
__global__ __launch_bounds__(256) void split_f32(const float* __restrict__ src,
                                                 unsigned short* __restrict__ hi,
                                                 unsigned short* __restrict__ lo, int n4) {
    const int i = blockIdx.x * 256 + threadIdx.x;
    if (i >= n4) return;
    const float4 v = ((const float4*)src)[i];
    ushort4 h, l;
    split2(v.x, h.x, l.x); split2(v.y, h.y, l.y);
    split2(v.z, h.z, l.z); split2(v.w, h.w, l.w);
    ((ushort4*)hi)[i] = h;
    ((ushort4*)lo)[i] = l;
}

__global__ __launch_bounds__(256) void bias2eff_kernel(const float* __restrict__ cb1,
                                                       const float* __restrict__ w2,
                                                       const float* __restrict__ b2,
                                                       float* __restrict__ out) {
    const int n = threadIdx.x;   // 256
    float s = 0.f;
    for (int k = 0; k < 1024; ++k) s = fmaf(cb1[k], w2[n * 1024 + k], s);
    out[n] = s + b2[n];
}

// cW2 [256,256] row-major -> transposed split bf16 pair [N=256 rows][K=256]
__global__ __launch_bounds__(256) void tsplit_kernel(const float* __restrict__ src,
                                                     unsigned short* __restrict__ hiT,
                                                     unsigned short* __restrict__ loT) {
    const int i = blockIdx.x * 256 + threadIdx.x;  // 65536
    const int r = i >> 8, c = i & 255;
    unsigned short h, l;
    split2(src[r * 256 + c], h, l);
    hiT[c * 256 + r] = h;
    loT[c * 256 + r] = l;
}

// ------------------------------------------- f32 prep GEMM (round-0 kernel, trimmed)
// C[m][n] = sum_k A[m*K+k] * W[n*K+k]   (B in [N,K] layout), no epilogue
constexpr int MT = 128, NT = 128, KT = 16, LDP = 132;

__global__ __launch_bounds__(256)
void prep_gemm(const float* __restrict__ A, const float* __restrict__ W,
               float* __restrict__ C, int M, int N, int K) {
    __shared__ float As[KT][LDP];
    __shared__ float Bs[KT][LDP];
    const int tid = threadIdx.x;
    const int bm = blockIdx.y, bn = blockIdx.x;
    const int tx = tid & 15, ty = tid >> 4;
    const int m0 = ty * 8, n0 = tx * 8;
    float acc[8][8];
#pragma unroll
    for (int i = 0; i < 8; ++i)
#pragma unroll
        for (int j = 0; j < 8; ++j) acc[i][j] = 0.f;
    const float* Ab = A + (size_t)(bm * MT) * K;
    const float* Wb = W + (size_t)(bn * NT) * K;
    for (int kt = 0; kt < K; kt += KT) {
#pragma unroll
        for (int l = 0; l < 2; ++l) {
            const int q = tid + l * 256;
            const int r = q >> 2;
            const int c = (q & 3) * 4;
            const float4 va = *(const float4*)(Ab + (size_t)r * K + kt + c);
            As[c + 0][r] = va.x; As[c + 1][r] = va.y; As[c + 2][r] = va.z; As[c + 3][r] = va.w;
            const float4 vb = *(const float4*)(Wb + (size_t)r * K + kt + c);
            Bs[c + 0][r] = vb.x; Bs[c + 1][r] = vb.y; Bs[c + 2][r] = vb.z; Bs[c + 3][r] = vb.w;
        }
        __syncthreads();
#pragma unroll
        for (int k = 0; k < KT; ++k) {
            const float4 a0 = *(const float4*)&As[k][m0];
            const float4 a1 = *(const float4*)&As[k][m0 + 4];
            const float4 b0 = *(const float4*)&Bs[k][n0];
            const float4 b1 = *(const float4*)&Bs[k][n0 + 4];
            const float a[8] = {a0.x, a0.y, a0.z, a0.w, a1.x, a1.y, a1.z, a1.w};
            const float b[8] = {b0.x, b0.y, b0.z, b0.w, b1.x, b1.y, b1.z, b1.w};
#pragma unroll
            for (int i = 0; i < 8; ++i)
#pragma unroll
                for (int j = 0; j < 8; ++j) acc[i][j] = fmaf(a[i], b[j], acc[i][j]);
        }
        __syncthreads();
    }
    const int gm0 = bm * MT + m0, gn0 = bn * NT + n0;
#pragma unroll
    for (int i = 0; i < 8; ++i) {
        float* Cp = C + (size_t)(gm0 + i) * N + gn0;
        *(float4*)Cp = make_float4(acc[i][0], acc[i][1], acc[i][2], acc[i][3]);
        *(float4*)(Cp + 4) = make_float4(acc[i][4], acc[i][5], acc[i][6], acc[i][7]);
    }
}

// ---------------------------------------------------------------- main MFMA GEMM
// BM=BN=128, BK=32, 256 thr (4 waves, 2x2), wave tile 64x64 = 4x4 frags 16x16.
// LDS layout granule-major: elem (row, g=k>>3, e=k&7) at [g*1024 + row*8 + e]
//  -> each 16-lane group's ds_read_b128 covers 256B contiguous: conflict-free.
template<bool A_F32, bool CHEB, bool OUT_F32>
__global__ __launch_bounds__(256)
void kan_mfma(const float* __restrict__ Af,
              const unsigned short* __restrict__ Ahg,
              const unsigned short* __restrict__ Alg,
              const unsigned short* __restrict__ Bhg,
              const unsigned short* __restrict__ Blg,
              const float* __restrict__ bias,
              const float* __restrict__ coeffs,
              float* __restrict__ Cf,
              unsigned short* __restrict__ Chh,
              unsigned short* __restrict__ Chl,
              int M, int N, int K)
{
    __shared__ __align__(16) unsigned short Ah[128 * 32];
    __shared__ __align__(16) unsigned short Al[128 * 32];
    __shared__ __align__(16) unsigned short Bh[128 * 32];
    __shared__ __align__(16) unsigned short Bl[128 * 32];

    const int tid = threadIdx.x;
    const int bm = blockIdx.y, bn = blockIdx.x;
    const int lane = tid & 63;
    const int wave = tid >> 6;
    const int wm = wave >> 1, wn = wave & 1;
    const int lr = lane & 15;   // row/col within 16x16 frag
    const int lg = lane >> 4;   // k-granule 0..3

    // staging coords: per iter l, thread covers granule (row = w*16+lr2 + l*64, g = lg2)
    const int s_row = (tid >> 6) * 16 + (tid & 15);  // 0..63
    const int s_g   = (tid >> 4) & 3;

    f32x4 acc[4][4];
#pragma unroll
    for (int m = 0; m < 4; ++m)
#pragma unroll
        for (int n = 0; n < 4; ++n) acc[m][n] = f32x4{0.f, 0.f, 0.f, 0.f};

    for (int kt = 0; kt < K; kt += 32) {
        // ---- stage A (128 rows x 32 k)
#pragma unroll
        for (int l = 0; l < 2; ++l) {
            const int row = s_row + l * 64;
            const int soff = s_g * 1024 + row * 8;
            if constexpr (A_F32) {
                const float* s = Af + (size_t)(bm * 128 + row) * K + kt + s_g * 8;
                const float4 v0 = *(const float4*)s;
                const float4 v1 = *(const float4*)(s + 4);
                const float f[8] = {v0.x, v0.y, v0.z, v0.w, v1.x, v1.y, v1.z, v1.w};
                short8 h8, l8;
#pragma unroll
                for (int e = 0; e < 8; ++e) {
                    unsigned short h, lo;
                    split2(f[e], h, lo);
                    h8[e] = (short)h; l8[e] = (short)lo;
                }
                *(short8*)&Ah[soff] = h8;
                *(short8*)&Al[soff] = l8;
            } else {
                const size_t go = (size_t)(bm * 128 + row) * K + kt + s_g * 8;
                *(short8*)&Ah[soff] = *(const short8*)(Ahg + go);
                *(short8*)&Al[soff] = *(const short8*)(Alg + go);
            }
        }
        // ---- stage B (bf16 pair, [N,K] layout)
#pragma unroll
        for (int l = 0; l < 2; ++l) {
            const int row = s_row + l * 64;
            const int soff = s_g * 1024 + row * 8;
            const size_t go = (size_t)(bn * 128 + row) * K + kt + s_g * 8;
            *(short8*)&Bh[soff] = *(const short8*)(Bhg + go);
            *(short8*)&Bl[soff] = *(const short8*)(Blg + go);
        }
        __syncthreads();

        short8 a_h[4], a_l[4], b_h[4], b_l[4];
#pragma unroll
        for (int m = 0; m < 4; ++m) {
            const int off = lg * 1024 + (wm * 64 + m * 16 + lr) * 8;
            a_h[m] = *(const short8*)&Ah[off];
            a_l[m] = *(const short8*)&Al[off];
        }
#pragma unroll
        for (int n = 0; n < 4; ++n) {
            const int off = lg * 1024 + (wn * 64 + n * 16 + lr) * 8;
            b_h[n] = *(const short8*)&Bh[off];
            b_l[n] = *(const short8*)&Bl[off];
        }
#pragma unroll
        for (int m = 0; m < 4; ++m)
#pragma unroll
            for (int n = 0; n < 4; ++n) {
                acc[m][n] = __builtin_amdgcn_mfma_f32_16x16x32_bf16(a_h[m], b_h[n], acc[m][n], 0, 0, 0);
                acc[m][n] = __builtin_amdgcn_mfma_f32_16x16x32_bf16(a_h[m], b_l[n], acc[m][n], 0, 0, 0);
                acc[m][n] = __builtin_amdgcn_mfma_f32_16x16x32_bf16(a_l[m], b_h[n], acc[m][n], 0, 0, 0);
            }
        __syncthreads();
    }

    // ---- epilogue: C/D layout col=lane&15, row=(lane>>4)*4+reg (m89/m91)
    const int gm0 = bm * 128 + wm * 64;
    const int gn0 = bn * 128 + wn * 64;
#pragma unroll
    for (int n = 0; n < 4; ++n) {
        const int colg = gn0 + n * 16 + lr;
        const float bia = bias[colg];
        float cf[8];
        if constexpr (CHEB) {
            const float4 u0 = *(const float4*)(coeffs + (size_t)colg * 8);
            const float4 u1 = *(const float4*)(coeffs + (size_t)colg * 8 + 4);
            cf[0] = u0.x; cf[1] = u0.y; cf[2] = u0.z; cf[3] = u0.w;
            cf[4] = u1.x; cf[5] = u1.y; cf[6] = u1.z; cf[7] = u1.w;
        }
#pragma unroll
        for (int m = 0; m < 4; ++m) {
            const int rowb = gm0 + m * 16 + lg * 4;
#pragma unroll
            for (int j = 0; j < 4; ++j) {
                const float alpha = acc[m][n][j] + bia;
                float v;
                if constexpr (CHEB) {
                    float tm2 = 1.f, tm1 = alpha;
                    v = fmaf(cf[1], alpha, cf[0]);
#pragma unroll
                    for (int d = 2; d < 8; ++d) {
                        const float t = 2.f * alpha * tm1 - tm2;
                        v = fmaf(cf[d], t, v);
                        tm2 = tm1; tm1 = t;
                    }
                } else {
                    v = alpha;
                }
                const size_t o = (size_t)(rowb + j) * N + colg;
                if constexpr (OUT_F32) {
                    Cf[o] = v;
                } else {
                    unsigned short h, l2;
                    split2(v, h, l2);
                    Chh[o] = h; Chl[o] = l2;
                }
            }
        }
    }
}

// ---------------------------------------------------------------- launch
extern "C" void kernel_launch(void* const* d_in, const int* in_sizes, int n_in,
                              void* d_out, int out_size, void* d_ws, size_t ws_size,
                              hipStream_t stream) {
    const float* x       = (const float*)d_in[0];
    const float* w1      = (const float*)d_in[1];
    const float* b1      = (const float*)d_in[2];
    const float* coeffs1 = (const float*)d_in[3];
    const float* cW1     = (const float*)d_in[4];
    const float* cb1     = (const float*)d_in[5];
    const float* w2      = (const float*)d_in[6];
    const float* b2      = (const float*)d_in[7];
    const float* coeffs2 = (const float*)d_in[8];
    const float* cW2     = (const float*)d_in[9];
    const float* cb2     = (const float*)d_in[10];

    constexpr int B  = 16384;
    constexpr int D1 = 1024;
    constexpr int D2 = 256;

    char* w = (char*)d_ws;
    size_t off = 0;
    auto alloc = [&](size_t bytes) { char* p = w + off; off += bytes; return p; };
    unsigned short* hh   = (unsigned short*)alloc((size_t)B * D1 * 2);
    unsigned short* hl   = (unsigned short*)alloc((size_t)B * D1 * 2);
    unsigned short* ph   = (unsigned short*)alloc((size_t)B * D2 * 2);
    unsigned short* pl   = (unsigned short*)alloc((size_t)B * D2 * 2);
    unsigned short* w1h  = (unsigned short*)alloc((size_t)D1 * D1 * 2);
    unsigned short* w1l  = (unsigned short*)alloc((size_t)D1 * D1 * 2);
    float*          m2tf = (float*)alloc((size_t)D2 * D1 * 4);
    unsigned short* m2h  = (unsigned short*)alloc((size_t)D2 * D1 * 2);
    unsigned short* m2l  = (unsigned short*)alloc((size_t)D2 * D1 * 2);
    unsigned short* cw2h = (unsigned short*)alloc((size_t)D2 * D2 * 2);
    unsigned short* cw2l = (unsigned short*)alloc((size_t)D2 * D2 * 2);
    float*          b2e  = (float*)alloc(D2 * 4);

    // prep: split w1; M2T = w2 . cW1^T (rows share K); bias2eff; transpose-split cW2
    split_f32<<<dim3((D1 * D1 / 4 + 255) / 256), dim3(256), 0, stream>>>(w1, w1h, w1l, D1 * D1 / 4);
    prep_gemm<<<dim3(D1 / NT, D2 / MT), dim3(256), 0, stream>>>(w2, cW1, m2tf, D2, D1, D1);
    split_f32<<<dim3((D2 * D1 / 4 + 255) / 256), dim3(256), 0, stream>>>(m2tf, m2h, m2l, D2 * D1 / 4);
    bias2eff_kernel<<<dim3(1), dim3(256), 0, stream>>>(cb1, w2, b2, b2e);
    tsplit_kernel<<<dim3(D2 * D2 / 256), dim3(256), 0, stream>>>(cW2, cw2h, cw2l);

    // G1: n1 = cheb1(x @ w1^T + b1) -> hh/hl
    kan_mfma<true, true, false><<<dim3(D1 / 128, B / 128), dim3(256), 0, stream>>>(
        x, nullptr, nullptr, w1h, w1l, b1, coeffs1, nullptr, hh, hl, B, D1, D1);
    // G3: p = cheb2(n1 @ M2T^T + bias2eff) -> ph/pl
    kan_mfma<false, true, false><<<dim3(D2 / 128, B / 128), dim3(256), 0, stream>>>(
        nullptr, hh, hl, m2h, m2l, b2e, coeffs2, nullptr, ph, pl, B, D2, D1);
    // G4: out = p @ cW2 + cb2 -> d_out (f32)
    kan_mfma<false, false, true><<<dim3(D2 / 128, B / 128), dim3(256), 0, stream>>>(
        nullptr, ph, pl, cw2h, cw2l, cb2, nullptr, (float*)d_out, nullptr, nullptr, B, D2, D2);
}

// Round 3
// 417.310 us; speedup vs baseline: 2.4645x; 1.1899x over previous
//
#include <hip/hip_runtime.h>

// FixedKAN round 3: split-bf16 3-product MFMA + global_load_lds staging.
//   xh/xl = split(x)                               (prep, HBM-bound)
//   n1 = cheb1(x @ w1^T + b1)                      G1 [16384,1024], K=1024
//   M2T = w2 . cW1^T (split-K fp32 prep), bias2eff = cb1.w2^T + b2
//   p  = cheb2(n1 @ M2T^T + bias2eff)              G3 [16384,256], K=1024
//   out = p @ cW2 + cb2                            G4 [16384,256], K=256
// GEMM: acc += AhBh + AhBl + AlBh (f32 16x16x32 bf16 MFMA), m97 structure
// (single-buffer LDS, 2 barriers/K-step, global_load_lds dwordx4).

typedef __attribute__((ext_vector_type(8))) short short8;
typedef __attribute__((ext_vector_type(4))) float f32x4;
typedef unsigned short ushort_t;

#define GAS(p) ((const __attribute__((address_space(1))) void*)(p))
#define LAS(p) ((__attribute__((address_space(3))) void*)(p))

__device__ __forceinline__ void split2(float f, ushort_t& h, ushort_t& l) {
    const unsigned u = __float_as_uint(f);
    h = (ushort_t)(u >> 16);                              // truncate hi
    const float hf = __uint_as_float(u & 0xFFFF0000u);
    l = (ushort_t)(__float_as_uint(f - hf) >> 16);        // truncate residual
}

// ---------------------------------------------------------------- prep kernels
__global__ __launch_bounds__(256) void split_f32(const float* __restrict__ src,
                                                 ushort_t* __restrict__ hi,
                                                 ushort_t* __restrict__ lo, int n4) {
    const int i = blockIdx.x * 256 + threadIdx.x;
    if (i >= n4) return;
    const float4 v = ((const float4*)src)[i];
    ushort4 h, l;
    split2(v.x, h.x, l.x); split2(v.y, h.y, l.y);
    split2(v.z, h.z, l.z); split2(v.w, h.w, l.w);
    ((ushort4*)hi)[i] = h;
    ((ushort4*)lo)[i] = l;
}

__global__ __launch_bounds__(256) void bias2eff_kernel(const float* __restrict__ cb1,
                                                       const float* __restrict__ w2,
                                                       const float* __restrict__ b2,
                                                       float* __restrict__ out) {
    const int n = threadIdx.x;   // 256
    float s = 0.f;
    for (int k = 0; k < 1024; ++k) s = fmaf(cb1[k], w2[n * 1024 + k], s);
    out[n] = s + b2[n];
}

// cW2 [256,256] row-major -> transposed split bf16 pair [N=256][K=256]
__global__ __launch_bounds__(256) void tsplit_kernel(const float* __restrict__ src,
                                                     ushort_t* __restrict__ hiT,
                                                     ushort_t* __restrict__ loT) {
    const int i = blockIdx.x * 256 + threadIdx.x;  // 65536
    const int r = i >> 8, c = i & 255;
    ushort_t h, l;
    split2(src[r * 256 + c], h, l);
    hiT[c * 256 + r] = h;
    loT[c * 256 + r] = l;
}

// split-K fp32 GEMM: Cp[z] partial of C[m][n] = sum_k A[m*K+k]*W[n*K+k]
// tile 64x64, 256 thr (16x16, 4x4 micro), K chunk = K/KS
constexpr int PKT = 16;
__global__ __launch_bounds__(256)
void prep_gemm_sk(const float* __restrict__ A, const float* __restrict__ W,
                  float* __restrict__ Cp, int M, int N, int K, int KS) {
    __shared__ float As[PKT][68];
    __shared__ float Bs[PKT][68];
    const int tid = threadIdx.x;
    const int bn = blockIdx.x, bm = blockIdx.y, bz = blockIdx.z;
    const int kc = K / KS, k0 = bz * kc;
    const int tx = tid & 15, ty = tid >> 4;
    float acc[4][4];
#pragma unroll
    for (int i = 0; i < 4; ++i)
#pragma unroll
        for (int j = 0; j < 4; ++j) acc[i][j] = 0.f;
    const float* Ab = A + (size_t)(bm * 64) * K + k0;
    const float* Wb = W + (size_t)(bn * 64) * K + k0;
    const int sr = tid >> 2;           // 0..63
    const int sc = (tid & 3) * 4;      // 0,4,8,12
    for (int kt = 0; kt < kc; kt += PKT) {
        const float4 va = *(const float4*)(Ab + (size_t)sr * K + kt + sc);
        As[sc + 0][sr] = va.x; As[sc + 1][sr] = va.y; As[sc + 2][sr] = va.z; As[sc + 3][sr] = va.w;
        const float4 vb = *(const float4*)(Wb + (size_t)sr * K + kt + sc);
        Bs[sc + 0][sr] = vb.x; Bs[sc + 1][sr] = vb.y; Bs[sc + 2][sr] = vb.z; Bs[sc + 3][sr] = vb.w;
        __syncthreads();
#pragma unroll
        for (int k = 0; k < PKT; ++k) {
            const float4 a4 = *(const float4*)&As[k][ty * 4];
            const float4 b4 = *(const float4*)&Bs[k][tx * 4];
            const float a[4] = {a4.x, a4.y, a4.z, a4.w};
            const float b[4] = {b4.x, b4.y, b4.z, b4.w};
#pragma unroll
            for (int i = 0; i < 4; ++i)
#pragma unroll
                for (int j = 0; j < 4; ++j) acc[i][j] = fmaf(a[i], b[j], acc[i][j]);
        }
        __syncthreads();
    }
    float* Cb = Cp + (size_t)bz * M * N + (size_t)(bm * 64 + ty * 4) * N + bn * 64 + tx * 4;
#pragma unroll
    for (int i = 0; i < 4; ++i)
        *(float4*)(Cb + (size_t)i * N) = make_float4(acc[i][0], acc[i][1], acc[i][2], acc[i][3]);
}

// sum KS partials, split to bf16 hi/lo
__global__ __launch_bounds__(256)
void combine_split(const float* __restrict__ Cp, ushort_t* __restrict__ hi,
                   ushort_t* __restrict__ lo, int n4, int KS) {
    const int i = blockIdx.x * 256 + threadIdx.x;
    if (i >= n4) return;
    float4 s = ((const float4*)Cp)[i];
    for (int z = 1; z < KS; ++z) {
        const float4 v = ((const float4*)Cp)[(size_t)z * n4 + i];
        s.x += v.x; s.y += v.y; s.z += v.z; s.w += v.w;
    }
    ushort4 h, l;
    split2(s.x, h.x, l.x); split2(s.y, h.y, l.y);
    split2(s.z, h.z, l.z); split2(s.w, h.w, l.w);
    ((ushort4*)hi)[i] = h;
    ((ushort4*)lo)[i] = l;
}

// ---------------------------------------------------------------- main MFMA GEMM
// BM=BN=128, BK=32, 256 thr (4 waves 2x2), wave tile 64x64 = 4x4 frags of 16x16x32.
// LDS granule-major: elem (row, g=k>>3, e=k&7) at ushort index g*1024 + row*8 + e.
// Staging via global_load_lds: wave w stages granule g=w of all 4 buffers,
// lane i -> row r0+i (LDS dest = uniform base + lane*16B, global addr per-lane).
template<bool CHEB, bool OUT_F32>
__global__ __launch_bounds__(256)
void kan_mfma(const ushort_t* __restrict__ Ahg,
              const ushort_t* __restrict__ Alg,
              const ushort_t* __restrict__ Bhg,
              const ushort_t* __restrict__ Blg,
              const float* __restrict__ bias,
              const float* __restrict__ coeffs,
              float* __restrict__ Cf,
              ushort_t* __restrict__ Chh,
              ushort_t* __restrict__ Chl,
              int M, int N, int K)
{
    __shared__ __align__(16) ushort_t Ah[128 * 32];
    __shared__ __align__(16) ushort_t Al[128 * 32];
    __shared__ __align__(16) ushort_t Bh[128 * 32];
    __shared__ __align__(16) ushort_t Bl[128 * 32];

    const int tid  = threadIdx.x;
    const int lane = tid & 63;
    const int wave = tid >> 6;

    // bijective XCD swizzle (nwg % 8 == 0 for all our grids)
    const int gx = gridDim.x;
    const int nwg = gx * gridDim.y;
    int wg = blockIdx.y * gx + blockIdx.x;
    wg = (wg & 7) * (nwg >> 3) + (wg >> 3);
    const int bn = wg % gx;
    const int bm = wg / gx;

    const int wm = wave >> 1, wn = wave & 1;
    const int lr = lane & 15;   // row/col within 16x16 frag
    const int lg = lane >> 4;   // k-granule 0..3

    f32x4 acc[4][4];
#pragma unroll
    for (int m = 0; m < 4; ++m)
#pragma unroll
        for (int n = 0; n < 4; ++n) acc[m][n] = f32x4{0.f, 0.f, 0.f, 0.f};

    // staging bases: wave w covers granule g = wave
    const size_t aRow0 = (size_t)(bm * 128);
    const size_t bRow0 = (size_t)(bn * 128);
    const int g = wave;
    const int ldsb = g * 1024;   // ushort index of granule-g block base

    for (int kt = 0; kt < K; kt += 32) {
        // ---- stage 32KB via 8 global_load_lds per wave
#pragma unroll
        for (int r0 = 0; r0 < 128; r0 += 64) {
            const size_t goA = (aRow0 + r0 + lane) * K + kt + g * 8;
            const size_t goB = (bRow0 + r0 + lane) * K + kt + g * 8;
            __builtin_amdgcn_global_load_lds(GAS(Ahg + goA), LAS(&Ah[ldsb + r0 * 8]), 16, 0, 0);
            __builtin_amdgcn_global_load_lds(GAS(Alg + goA), LAS(&Al[ldsb + r0 * 8]), 16, 0, 0);
            __builtin_amdgcn_global_load_lds(GAS(Bhg + goB), LAS(&Bh[ldsb + r0 * 8]), 16, 0, 0);
            __builtin_amdgcn_global_load_lds(GAS(Blg + goB), LAS(&Bl[ldsb + r0 * 8]), 16, 0, 0);
        }
        __syncthreads();

        short8 a_h[4], a_l[4], b_h[4], b_l[4];
#pragma unroll
        for (int m = 0; m < 4; ++m) {
            const int off = lg * 1024 + (wm * 64 + m * 16 + lr) * 8;
            a_h[m] = *(const short8*)&Ah[off];
            a_l[m] = *(const short8*)&Al[off];
        }
#pragma unroll
        for (int n = 0; n < 4; ++n) {
            const int off = lg * 1024 + (wn * 64 + n * 16 + lr) * 8;
            b_h[n] = *(const short8*)&Bh[off];
            b_l[n] = *(const short8*)&Bl[off];
        }
#pragma unroll
        for (int m = 0; m < 4; ++m)
#pragma unroll
            for (int n = 0; n < 4; ++n) {
                acc[m][n] = __builtin_amdgcn_mfma_f32_16x16x32_bf16(a_h[m], b_h[n], acc[m][n], 0, 0, 0);
                acc[m][n] = __builtin_amdgcn_mfma_f32_16x16x32_bf16(a_h[m], b_l[n], acc[m][n], 0, 0, 0);
                acc[m][n] = __builtin_amdgcn_mfma_f32_16x16x32_bf16(a_l[m], b_h[n], acc[m][n], 0, 0, 0);
            }
        __syncthreads();
    }

    // ---- epilogue: C/D layout col=lane&15, row=(lane>>4)*4+reg (m89/m91)
    const int gm0 = bm * 128 + wm * 64;
    const int gn0 = bn * 128 + wn * 64;
#pragma unroll
    for (int n = 0; n < 4; ++n) {
        const int colg = gn0 + n * 16 + lr;
        const float bia = bias[colg];
        float cf[8];
        if constexpr (CHEB) {
            const float4 u0 = *(const float4*)(coeffs + (size_t)colg * 8);
            const float4 u1 = *(const float4*)(coeffs + (size_t)colg * 8 + 4);
            cf[0] = u0.x; cf[1] = u0.y; cf[2] = u0.z; cf[3] = u0.w;
            cf[4] = u1.x; cf[5] = u1.y; cf[6] = u1.z; cf[7] = u1.w;
        }
#pragma unroll
        for (int m = 0; m < 4; ++m) {
            const int rowb = gm0 + m * 16 + lg * 4;
#pragma unroll
            for (int j = 0; j < 4; ++j) {
                const float alpha = acc[m][n][j] + bia;
                float v;
                if constexpr (CHEB) {
                    float tm2 = 1.f, tm1 = alpha;
                    v = fmaf(cf[1], alpha, cf[0]);
#pragma unroll
                    for (int d = 2; d < 8; ++d) {
                        const float t = 2.f * alpha * tm1 - tm2;
                        v = fmaf(cf[d], t, v);
                        tm2 = tm1; tm1 = t;
                    }
                } else {
                    v = alpha;
                }
                const size_t o = (size_t)(rowb + j) * N + colg;
                if constexpr (OUT_F32) {
                    Cf[o] = v;
                } else {
                    ushort_t h, l2;
                    split2(v, h, l2);
                    Chh[o] = h; Chl[o] = l2;
                }
            }
        }
    }
}

// ---------------------------------------------------------------- launch
extern "C" void kernel_launch(void* const* d_in, const int* in_sizes, int n_in,
                              void* d_out, int out_size, void* d_ws, size_t ws_size,
                              hipStream_t stream) {
    const float* x       = (const float*)d_in[0];
    const float* w1      = (const float*)d_in[1];
    const float* b1      = (const float*)d_in[2];
    const float* coeffs1 = (const float*)d_in[3];
    const float* cW1     = (const float*)d_in[4];
    const float* cb1     = (const float*)d_in[5];
    const float* w2      = (const float*)d_in[6];
    const float* b2      = (const float*)d_in[7];
    const float* coeffs2 = (const float*)d_in[8];
    const float* cW2     = (const float*)d_in[9];
    const float* cb2     = (const float*)d_in[10];

    constexpr int B  = 16384;
    constexpr int D1 = 1024;
    constexpr int D2 = 256;
    constexpr int KS = 4;      // split-K factor for prep

    char* w = (char*)d_ws;
    size_t off = 0;
    auto alloc = [&](size_t bytes) { char* p = w + off; off += (bytes + 255) & ~(size_t)255; return p; };
    ushort_t* xh   = (ushort_t*)alloc((size_t)B * D1 * 2);
    ushort_t* xl   = (ushort_t*)alloc((size_t)B * D1 * 2);
    ushort_t* hh   = (ushort_t*)alloc((size_t)B * D1 * 2);
    ushort_t* hl   = (ushort_t*)alloc((size_t)B * D1 * 2);
    ushort_t* ph   = (ushort_t*)alloc((size_t)B * D2 * 2);
    ushort_t* pl   = (ushort_t*)alloc((size_t)B * D2 * 2);
    ushort_t* w1h  = (ushort_t*)alloc((size_t)D1 * D1 * 2);
    ushort_t* w1l  = (ushort_t*)alloc((size_t)D1 * D1 * 2);
    float*    m2p  = (float*)alloc((size_t)KS * D2 * D1 * 4);
    ushort_t* m2h  = (ushort_t*)alloc((size_t)D2 * D1 * 2);
    ushort_t* m2l  = (ushort_t*)alloc((size_t)D2 * D1 * 2);
    ushort_t* cw2h = (ushort_t*)alloc((size_t)D2 * D2 * 2);
    ushort_t* cw2l = (ushort_t*)alloc((size_t)D2 * D2 * 2);
    float*    b2e  = (float*)alloc(D2 * 4);

    // ---- prep
    split_f32<<<dim3(B * D1 / 4 / 256), dim3(256), 0, stream>>>(x, xh, xl, B * D1 / 4);
    split_f32<<<dim3(D1 * D1 / 4 / 256), dim3(256), 0, stream>>>(w1, w1h, w1l, D1 * D1 / 4);
    prep_gemm_sk<<<dim3(D1 / 64, D2 / 64, KS), dim3(256), 0, stream>>>(w2, cW1, m2p, D2, D1, D1, KS);
    combine_split<<<dim3(D2 * D1 / 4 / 256), dim3(256), 0, stream>>>(m2p, m2h, m2l, D2 * D1 / 4, KS);
    bias2eff_kernel<<<dim3(1), dim3(256), 0, stream>>>(cb1, w2, b2, b2e);
    tsplit_kernel<<<dim3(D2 * D2 / 256), dim3(256), 0, stream>>>(cW2, cw2h, cw2l);

    // ---- main pipeline
    // G1: n1 = cheb1(x @ w1^T + b1) -> hh/hl
    kan_mfma<true, false><<<dim3(D1 / 128, B / 128), dim3(256), 0, stream>>>(
        xh, xl, w1h, w1l, b1, coeffs1, nullptr, hh, hl, B, D1, D1);
    // G3: p = cheb2(n1 @ M2T^T + bias2eff) -> ph/pl
    kan_mfma<true, false><<<dim3(D2 / 128, B / 128), dim3(256), 0, stream>>>(
        hh, hl, m2h, m2l, b2e, coeffs2, nullptr, ph, pl, B, D2, D1);
    // G4: out = p @ cW2 + cb2 -> d_out (f32)
    kan_mfma<false, true><<<dim3(D2 / 128, B / 128), dim3(256), 0, stream>>>(
        ph, pl, cw2h, cw2l, cb2, nullptr, (float*)d_out, nullptr, nullptr, B, D2, D2);
}

// Round 5
// 355.024 us; speedup vs baseline: 2.8969x; 1.1754x over previous
//
#include <hip/hip_runtime.h>

// FixedKAN round 4 (resubmit after broker timeout): split-bf16 3-product MFMA.
//  G1: 256^2-tile 8-wave deep-pipelined kernel (4-phase/K-tile, dbuf LDS,
//      counted-vmcnt schedule, setprio) -- cheb1(x @ w1^T + b1) -> hh/hl
//  G3: 128^2 kernel  p = cheb2(n1 @ M2T^T + bias2eff) -> ph/pl
//  G4: 128^2 kernel  out = p @ cW2 + cb2 -> f32
// GEMM core: A=Ah+Al, B=Bh+Bl bf16; acc += AhBh + AhBl + AlBh (f32 MFMA).

typedef __attribute__((ext_vector_type(8))) short short8;
typedef __attribute__((ext_vector_type(4))) float f32x4;
typedef unsigned short ushort_t;

#define GAS(p) ((const __attribute__((address_space(1))) void*)(p))
#define LAS(p) ((__attribute__((address_space(3))) void*)(p))

__device__ __forceinline__ void split2(float f, ushort_t& h, ushort_t& l) {
    const unsigned u = __float_as_uint(f);
    h = (ushort_t)(u >> 16);                              // truncate hi
    const float hf = __uint_as_float(u & 0xFFFF0000u);
    l = (ushort_t)(__float_as_uint(f - hf) >> 16);        // truncate residual
}

// ---------------------------------------------------------------- prep kernels
__global__ __launch_bounds__(256) void split_f32(const float* __restrict__ src,
                                                 ushort_t* __restrict__ hi,
                                                 ushort_t* __restrict__ lo, int n4) {
    const int i = blockIdx.x * 256 + threadIdx.x;
    if (i >= n4) return;
    const float4 v = ((const float4*)src)[i];
    ushort4 h, l;
    split2(v.x, h.x, l.x); split2(v.y, h.y, l.y);
    split2(v.z, h.z, l.z); split2(v.w, h.w, l.w);
    ((ushort4*)hi)[i] = h;
    ((ushort4*)lo)[i] = l;
}

// bias2eff[n] = dot(cb1, w2[n,:]) + b2[n]; 64 blocks x 4 waves, one wave per n
__global__ __launch_bounds__(256) void bias2eff_kernel(const float* __restrict__ cb1,
                                                       const float* __restrict__ w2,
                                                       const float* __restrict__ b2,
                                                       float* __restrict__ out) {
    const int wave = threadIdx.x >> 6, lane = threadIdx.x & 63;
    const int n = blockIdx.x * 4 + wave;
    const float4* row = (const float4*)(w2 + (size_t)n * 1024);
    const float4* c4  = (const float4*)cb1;
    float s = 0.f;
#pragma unroll
    for (int i = 0; i < 4; ++i) {
        const int idx = lane + i * 64;
        const float4 a = row[idx], c = c4[idx];
        s += a.x * c.x + a.y * c.y + a.z * c.z + a.w * c.w;
    }
#pragma unroll
    for (int off = 32; off; off >>= 1) s += __shfl_down(s, off);
    if (lane == 0) out[n] = s + b2[n];
}

// cW2 [256,256] row-major -> transposed split bf16 pair [N=256][K=256]
__global__ __launch_bounds__(256) void tsplit_kernel(const float* __restrict__ src,
                                                     ushort_t* __restrict__ hiT,
                                                     ushort_t* __restrict__ loT) {
    const int i = blockIdx.x * 256 + threadIdx.x;  // 65536
    const int r = i >> 8, c = i & 255;
    ushort_t h, l;
    split2(src[r * 256 + c], h, l);
    hiT[c * 256 + r] = h;
    loT[c * 256 + r] = l;
}

// split-K fp32 GEMM: Cp[z] partial of C[m][n] = sum_k A[m*K+k]*W[n*K+k]
constexpr int PKT = 16;
__global__ __launch_bounds__(256)
void prep_gemm_sk(const float* __restrict__ A, const float* __restrict__ W,
                  float* __restrict__ Cp, int M, int N, int K, int KS) {
    __shared__ float As[PKT][68];
    __shared__ float Bs[PKT][68];
    const int tid = threadIdx.x;
    const int bn = blockIdx.x, bm = blockIdx.y, bz = blockIdx.z;
    const int kc = K / KS, k0 = bz * kc;
    const int tx = tid & 15, ty = tid >> 4;
    float acc[4][4];
#pragma unroll
    for (int i = 0; i < 4; ++i)
#pragma unroll
        for (int j = 0; j < 4; ++j) acc[i][j] = 0.f;
    const float* Ab = A + (size_t)(bm * 64) * K + k0;
    const float* Wb = W + (size_t)(bn * 64) * K + k0;
    const int sr = tid >> 2;
    const int sc = (tid & 3) * 4;
    for (int kt = 0; kt < kc; kt += PKT) {
        const float4 va = *(const float4*)(Ab + (size_t)sr * K + kt + sc);
        As[sc + 0][sr] = va.x; As[sc + 1][sr] = va.y; As[sc + 2][sr] = va.z; As[sc + 3][sr] = va.w;
        const float4 vb = *(const float4*)(Wb + (size_t)sr * K + kt + sc);
        Bs[sc + 0][sr] = vb.x; Bs[sc + 1][sr] = vb.y; Bs[sc + 2][sr] = vb.z; Bs[sc + 3][sr] = vb.w;
        __syncthreads();
#pragma unroll
        for (int k = 0; k < PKT; ++k) {
            const float4 a4 = *(const float4*)&As[k][ty * 4];
            const float4 b4 = *(const float4*)&Bs[k][tx * 4];
            const float a[4] = {a4.x, a4.y, a4.z, a4.w};
            const float b[4] = {b4.x, b4.y, b4.z, b4.w};
#pragma unroll
            for (int i = 0; i < 4; ++i)
#pragma unroll
                for (int j = 0; j < 4; ++j) acc[i][j] = fmaf(a[i], b[j], acc[i][j]);
        }
        __syncthreads();
    }
    float* Cb = Cp + (size_t)bz * M * N + (size_t)(bm * 64 + ty * 4) * N + bn * 64 + tx * 4;
#pragma unroll
    for (int i = 0; i < 4; ++i)
        *(float4*)(Cb + (size_t)i * N) = make_float4(acc[i][0], acc[i][1], acc[i][2], acc[i][3]);
}

__global__ __launch_bounds__(256)
void combine_split(const float* __restrict__ Cp, ushort_t* __restrict__ hi,
                   ushort_t* __restrict__ lo, int n4, int KS) {
    const int i = blockIdx.x * 256 + threadIdx.x;
    if (i >= n4) return;
    float4 s = ((const float4*)Cp)[i];
    for (int z = 1; z < KS; ++z) {
        const float4 v = ((const float4*)Cp)[(size_t)z * n4 + i];
        s.x += v.x; s.y += v.y; s.z += v.z; s.w += v.w;
    }
    ushort4 h, l;
    split2(s.x, h.x, l.x); split2(s.y, h.y, l.y);
    split2(s.z, h.z, l.z); split2(s.w, h.w, l.w);
    ((ushort4*)hi)[i] = h;
    ((ushort4*)lo)[i] = l;
}

// ================================================================ G1 kernel
// 256x256 tile, BK=32, 512 thr (8 waves 2Mx4N), wave tile 128x64 (8x4 frags).
// LDS: 2 sets x {Ah,Al,Bh,Bl} x 256rows x 32k bf16 = 128 KB, granule-major:
//   elem(row, g=k>>3, e=k&7) at ushort idx g*2048 + row*8 + e  -> ds_read_b128
//   per 16-lane group covers 256B contiguous: conflict-free, gload_lds-linear.
// Schedule: 4 phases/K-tile {ds_read quadrant || issue 2 stage loads ->
//   barrier -> lgkmcnt(0) -> setprio(1) 24 MFMA setprio(0) -> barrier};
//   vmcnt(0) ONCE per K-tile (loads have ~1-4 phases of MFMA cover).
__global__ __launch_bounds__(512, 2)
void kan_mfma256(const ushort_t* __restrict__ Ahg,
                 const ushort_t* __restrict__ Alg,
                 const ushort_t* __restrict__ Bhg,
                 const ushort_t* __restrict__ Blg,
                 const float* __restrict__ bias,
                 const float* __restrict__ coeffs,
                 ushort_t* __restrict__ Chh,
                 ushort_t* __restrict__ Chl,
                 int M, int N, int K)
{
    __shared__ __align__(16) ushort_t LDS[2][4][256 * 32];  // [set][Ah,Al,Bh,Bl]

    const int tid  = threadIdx.x;
    const int lane = tid & 63;
    const int wave = tid >> 6;

    // bijective XCD swizzle (nwg = 256, %8==0)
    const int gx  = gridDim.x;
    const int nwg = gx * gridDim.y;
    int wg = blockIdx.y * gx + blockIdx.x;
    wg = (wg & 7) * (nwg >> 3) + (wg >> 3);
    const int bn = wg % gx;
    const int bm = wg / gx;

    const int wm = wave >> 2;        // 0..1  (M half)
    const int wn = wave & 3;         // 0..3  (N quarter)
    const int lr = lane & 15;
    const int lg = lane >> 4;

    // staging role: wave covers granule g = wave&3, row chunk (wave>>2)*128
    const int sg  = wave & 3;
    const int r0a = (wave >> 2) * 128;
    const size_t aRow0 = (size_t)bm * 256;
    const size_t bRow0 = (size_t)bn * 256;

    f32x4 acc[8][4];
#pragma unroll
    for (int m = 0; m < 8; ++m)
#pragma unroll
        for (int n = 0; n < 4; ++n) acc[m][n] = f32x4{0.f, 0.f, 0.f, 0.f};

    // stage phase-q pair of loads for tile starting at kt into set s
    auto stage = [&](int q, int s, int kt) {
        const int r0 = r0a + ((q & 1) ? 64 : 0);
        const int lo = (q >= 2) ? 1 : 0;
        const size_t ga = (aRow0 + r0 + lane) * K + kt + sg * 8;
        const size_t gb = (bRow0 + r0 + lane) * K + kt + sg * 8;
        const int di = sg * 2048 + r0 * 8;
        __builtin_amdgcn_global_load_lds(GAS((lo ? Alg : Ahg) + ga),
                                         LAS(&LDS[s][lo][di]), 16, 0, 0);
        __builtin_amdgcn_global_load_lds(GAS((lo ? Blg : Bhg) + gb),
                                         LAS(&LDS[s][2 + lo][di]), 16, 0, 0);
    };

    // prologue: stage tile 0 into set 0
#pragma unroll
    for (int q = 0; q < 4; ++q) stage(q, 0, 0);
    asm volatile("s_waitcnt vmcnt(0)" ::: "memory");
    __builtin_amdgcn_s_barrier();

    const int nt = K >> 5;
    constexpr int MH[4] = {0, 1, 1, 0};
    constexpr int NH[4] = {0, 0, 1, 1};

    for (int t = 0; t < nt; ++t) {
        const int cur = t & 1;
        const int kt_next = (t + 1) << 5;
        const bool more = (t + 1) < nt;

#pragma unroll
        for (int q = 0; q < 4; ++q) {
            const int mh = MH[q], nh = NH[q];
            // ds_read quadrant fragments
            short8 ah[4], al4[4], bh2[2], bl2[2];
#pragma unroll
            for (int m = 0; m < 4; ++m) {
                const int idx = lg * 2048 + (wm * 128 + (mh * 4 + m) * 16 + lr) * 8;
                ah[m]  = *(const short8*)&LDS[cur][0][idx];
                al4[m] = *(const short8*)&LDS[cur][1][idx];
            }
#pragma unroll
            for (int n = 0; n < 2; ++n) {
                const int idx = lg * 2048 + (wn * 64 + (nh * 2 + n) * 16 + lr) * 8;
                bh2[n] = *(const short8*)&LDS[cur][2][idx];
                bl2[n] = *(const short8*)&LDS[cur][3][idx];
            }
            // issue this phase's prefetch pair for tile t+1
            if (more) stage(q, cur ^ 1, kt_next);

            __builtin_amdgcn_s_barrier();
            asm volatile("s_waitcnt lgkmcnt(0)" ::: "memory");
            __builtin_amdgcn_sched_barrier(0);
            __builtin_amdgcn_s_setprio(1);
#pragma unroll
            for (int m = 0; m < 4; ++m)
#pragma unroll
                for (int n = 0; n < 2; ++n) {
                    const int am = mh * 4 + m, an = nh * 2 + n;
                    acc[am][an] = __builtin_amdgcn_mfma_f32_16x16x32_bf16(ah[m],  bh2[n], acc[am][an], 0, 0, 0);
                    acc[am][an] = __builtin_amdgcn_mfma_f32_16x16x32_bf16(ah[m],  bl2[n], acc[am][an], 0, 0, 0);
                    acc[am][an] = __builtin_amdgcn_mfma_f32_16x16x32_bf16(al4[m], bh2[n], acc[am][an], 0, 0, 0);
                }
            __builtin_amdgcn_s_setprio(0);
            __builtin_amdgcn_s_barrier();
        }

        if (more) {
            asm volatile("s_waitcnt vmcnt(0)" ::: "memory");  // drain t+1 loads (covered by 1-4 MFMA phases)
            __builtin_amdgcn_s_barrier();
        }
    }

    // ---- epilogue: bias + cheb + split store. C/D: col=lane&15, row=(lane>>4)*4+j
    const int gm0 = bm * 256 + wm * 128;
    const int gn0 = bn * 256 + wn * 64;
#pragma unroll
    for (int n = 0; n < 4; ++n) {
        const int colg = gn0 + n * 16 + lr;
        const float bia = bias[colg];
        float cf[8];
        {
            const float4 u0 = *(const float4*)(coeffs + (size_t)colg * 8);
            const float4 u1 = *(const float4*)(coeffs + (size_t)colg * 8 + 4);
            cf[0] = u0.x; cf[1] = u0.y; cf[2] = u0.z; cf[3] = u0.w;
            cf[4] = u1.x; cf[5] = u1.y; cf[6] = u1.z; cf[7] = u1.w;
        }
#pragma unroll
        for (int m = 0; m < 8; ++m) {
            const int rowb = gm0 + m * 16 + lg * 4;
#pragma unroll
            for (int j = 0; j < 4; ++j) {
                const float alpha = acc[m][n][j] + bia;
                float tm2 = 1.f, tm1 = alpha;
                float v = fmaf(cf[1], alpha, cf[0]);
#pragma unroll
                for (int d = 2; d < 8; ++d) {
                    const float tch = 2.f * alpha * tm1 - tm2;
                    v = fmaf(cf[d], tch, v);
                    tm2 = tm1; tm1 = tch;
                }
                const size_t o = (size_t)(rowb + j) * N + colg;
                ushort_t h, l2;
                split2(v, h, l2);
                Chh[o] = h; Chl[o] = l2;
            }
        }
    }
}

// ================================================================ 128^2 kernel (G3/G4)
template<bool CHEB, bool OUT_F32>
__global__ __launch_bounds__(256)
void kan_mfma(const ushort_t* __restrict__ Ahg,
              const ushort_t* __restrict__ Alg,
              const ushort_t* __restrict__ Bhg,
              const ushort_t* __restrict__ Blg,
              const float* __restrict__ bias,
              const float* __restrict__ coeffs,
              float* __restrict__ Cf,
              ushort_t* __restrict__ Chh,
              ushort_t* __restrict__ Chl,
              int M, int N, int K)
{
    __shared__ __align__(16) ushort_t Ah[128 * 32];
    __shared__ __align__(16) ushort_t Al[128 * 32];
    __shared__ __align__(16) ushort_t Bh[128 * 32];
    __shared__ __align__(16) ushort_t Bl[128 * 32];

    const int tid  = threadIdx.x;
    const int lane = tid & 63;
    const int wave = tid >> 6;

    const int gx = gridDim.x;
    const int nwg = gx * gridDim.y;
    int wg = blockIdx.y * gx + blockIdx.x;
    wg = (wg & 7) * (nwg >> 3) + (wg >> 3);
    const int bn = wg % gx;
    const int bm = wg / gx;

    const int wm = wave >> 1, wn = wave & 1;
    const int lr = lane & 15;
    const int lg = lane >> 4;

    f32x4 acc[4][4];
#pragma unroll
    for (int m = 0; m < 4; ++m)
#pragma unroll
        for (int n = 0; n < 4; ++n) acc[m][n] = f32x4{0.f, 0.f, 0.f, 0.f};

    const size_t aRow0 = (size_t)(bm * 128);
    const size_t bRow0 = (size_t)(bn * 128);
    const int g = wave;
    const int ldsb = g * 1024;

    for (int kt = 0; kt < K; kt += 32) {
#pragma unroll
        for (int r0 = 0; r0 < 128; r0 += 64) {
            const size_t goA = (aRow0 + r0 + lane) * K + kt + g * 8;
            const size_t goB = (bRow0 + r0 + lane) * K + kt + g * 8;
            __builtin_amdgcn_global_load_lds(GAS(Ahg + goA), LAS(&Ah[ldsb + r0 * 8]), 16, 0, 0);
            __builtin_amdgcn_global_load_lds(GAS(Alg + goA), LAS(&Al[ldsb + r0 * 8]), 16, 0, 0);
            __builtin_amdgcn_global_load_lds(GAS(Bhg + goB), LAS(&Bh[ldsb + r0 * 8]), 16, 0, 0);
            __builtin_amdgcn_global_load_lds(GAS(Blg + goB), LAS(&Bl[ldsb + r0 * 8]), 16, 0, 0);
        }
        __syncthreads();

        short8 a_h[4], a_l[4], b_h[4], b_l[4];
#pragma unroll
        for (int m = 0; m < 4; ++m) {
            const int off = lg * 1024 + (wm * 64 + m * 16 + lr) * 8;
            a_h[m] = *(const short8*)&Ah[off];
            a_l[m] = *(const short8*)&Al[off];
        }
#pragma unroll
        for (int n = 0; n < 4; ++n) {
            const int off = lg * 1024 + (wn * 64 + n * 16 + lr) * 8;
            b_h[n] = *(const short8*)&Bh[off];
            b_l[n] = *(const short8*)&Bl[off];
        }
#pragma unroll
        for (int m = 0; m < 4; ++m)
#pragma unroll
            for (int n = 0; n < 4; ++n) {
                acc[m][n] = __builtin_amdgcn_mfma_f32_16x16x32_bf16(a_h[m], b_h[n], acc[m][n], 0, 0, 0);
                acc[m][n] = __builtin_amdgcn_mfma_f32_16x16x32_bf16(a_h[m], b_l[n], acc[m][n], 0, 0, 0);
                acc[m][n] = __builtin_amdgcn_mfma_f32_16x16x32_bf16(a_l[m], b_h[n], acc[m][n], 0, 0, 0);
            }
        __syncthreads();
    }

    const int gm0 = bm * 128 + wm * 64;
    const int gn0 = bn * 128 + wn * 64;
#pragma unroll
    for (int n = 0; n < 4; ++n) {
        const int colg = gn0 + n * 16 + lr;
        const float bia = bias[colg];
        float cf[8];
        if constexpr (CHEB) {
            const float4 u0 = *(const float4*)(coeffs + (size_t)colg * 8);
            const float4 u1 = *(const float4*)(coeffs + (size_t)colg * 8 + 4);
            cf[0] = u0.x; cf[1] = u0.y; cf[2] = u0.z; cf[3] = u0.w;
            cf[4] = u1.x; cf[5] = u1.y; cf[6] = u1.z; cf[7] = u1.w;
        }
#pragma unroll
        for (int m = 0; m < 4; ++m) {
            const int rowb = gm0 + m * 16 + lg * 4;
#pragma unroll
            for (int j = 0; j < 4; ++j) {
                const float alpha = acc[m][n][j] + bia;
                float v;
                if constexpr (CHEB) {
                    float tm2 = 1.f, tm1 = alpha;
                    v = fmaf(cf[1], alpha, cf[0]);
#pragma unroll
                    for (int d = 2; d < 8; ++d) {
                        const float t = 2.f * alpha * tm1 - tm2;
                        v = fmaf(cf[d], t, v);
                        tm2 = tm1; tm1 = t;
                    }
                } else {
                    v = alpha;
                }
                const size_t o = (size_t)(rowb + j) * N + colg;
                if constexpr (OUT_F32) {
                    Cf[o] = v;
                } else {
                    ushort_t h, l2;
                    split2(v, h, l2);
                    Chh[o] = h; Chl[o] = l2;
                }
            }
        }
    }
}

// ---------------------------------------------------------------- launch
extern "C" void kernel_launch(void* const* d_in, const int* in_sizes, int n_in,
                              void* d_out, int out_size, void* d_ws, size_t ws_size,
                              hipStream_t stream) {
    const float* x       = (const float*)d_in[0];
    const float* w1      = (const float*)d_in[1];
    const float* b1      = (const float*)d_in[2];
    const float* coeffs1 = (const float*)d_in[3];
    const float* cW1     = (const float*)d_in[4];
    const float* cb1     = (const float*)d_in[5];
    const float* w2      = (const float*)d_in[6];
    const float* b2      = (const float*)d_in[7];
    const float* coeffs2 = (const float*)d_in[8];
    const float* cW2     = (const float*)d_in[9];
    const float* cb2     = (const float*)d_in[10];

    constexpr int B  = 16384;
    constexpr int D1 = 1024;
    constexpr int D2 = 256;
    constexpr int KS = 4;

    char* w = (char*)d_ws;
    size_t off = 0;
    auto alloc = [&](size_t bytes) { char* p = w + off; off += (bytes + 255) & ~(size_t)255; return p; };
    ushort_t* xh   = (ushort_t*)alloc((size_t)B * D1 * 2);
    ushort_t* xl   = (ushort_t*)alloc((size_t)B * D1 * 2);
    ushort_t* hh   = (ushort_t*)alloc((size_t)B * D1 * 2);
    ushort_t* hl   = (ushort_t*)alloc((size_t)B * D1 * 2);
    ushort_t* ph   = (ushort_t*)alloc((size_t)B * D2 * 2);
    ushort_t* pl   = (ushort_t*)alloc((size_t)B * D2 * 2);
    ushort_t* w1h  = (ushort_t*)alloc((size_t)D1 * D1 * 2);
    ushort_t* w1l  = (ushort_t*)alloc((size_t)D1 * D1 * 2);
    float*    m2p  = (float*)alloc((size_t)KS * D2 * D1 * 4);
    ushort_t* m2h  = (ushort_t*)alloc((size_t)D2 * D1 * 2);
    ushort_t* m2l  = (ushort_t*)alloc((size_t)D2 * D1 * 2);
    ushort_t* cw2h = (ushort_t*)alloc((size_t)D2 * D2 * 2);
    ushort_t* cw2l = (ushort_t*)alloc((size_t)D2 * D2 * 2);
    float*    b2e  = (float*)alloc(D2 * 4);

    // ---- prep
    split_f32<<<dim3(B * D1 / 4 / 256), dim3(256), 0, stream>>>(x, xh, xl, B * D1 / 4);
    split_f32<<<dim3(D1 * D1 / 4 / 256), dim3(256), 0, stream>>>(w1, w1h, w1l, D1 * D1 / 4);
    prep_gemm_sk<<<dim3(D1 / 64, D2 / 64, KS), dim3(256), 0, stream>>>(w2, cW1, m2p, D2, D1, D1, KS);
    combine_split<<<dim3(D2 * D1 / 4 / 256), dim3(256), 0, stream>>>(m2p, m2h, m2l, D2 * D1 / 4, KS);
    bias2eff_kernel<<<dim3(D2 / 4), dim3(256), 0, stream>>>(cb1, w2, b2, b2e);
    tsplit_kernel<<<dim3(D2 * D2 / 256), dim3(256), 0, stream>>>(cW2, cw2h, cw2l);

    // ---- main pipeline
    // G1: n1 = cheb1(x @ w1^T + b1) -> hh/hl   (256^2 pipelined kernel)
    kan_mfma256<<<dim3(D1 / 256, B / 256), dim3(512), 0, stream>>>(
        xh, xl, w1h, w1l, b1, coeffs1, hh, hl, B, D1, D1);
    // G3: p = cheb2(n1 @ M2T^T + bias2eff) -> ph/pl
    kan_mfma<true, false><<<dim3(D2 / 128, B / 128), dim3(256), 0, stream>>>(
        hh, hl, m2h, m2l, b2e, coeffs2, nullptr, ph, pl, B, D2, D1);
    // G4: out = p @ cW2 + cb2 -> d_out (f32)
    kan_mfma<false, true><<<dim3(D2 / 128, B / 128), dim3(256), 0, stream>>>(
        ph, pl, cw2h, cw2l, cb2, nullptr, (float*)d_out, nullptr, nullptr, B, D2, D2);
}

// Round 6
// 339.339 us; speedup vs baseline: 3.0308x; 1.0462x over previous
//
#include <hip/hip_runtime.h>

// FixedKAN round 6: split-bf16 3-product MFMA, 2-phase double-buffered schedule.
//  G1: 256^2/BK=32 dbuf, 8 waves, each frag read ONCE per K-tile (B once,
//      A in two clusters), 1 barrier + 1 vmcnt(0) per K-tile.
//  G3/G4: 128^2/BK=32 dbuf (64 KB LDS -> 2 blocks/CU), same schedule.
//  Prep fused into 3 launches.
// GEMM core: A=Ah+Al, B=Bh+Bl bf16; acc += AhBh + AhBl + AlBh (f32 MFMA).

typedef __attribute__((ext_vector_type(8))) short short8;
typedef __attribute__((ext_vector_type(4))) float f32x4;
typedef unsigned short ushort_t;

#define GAS(p) ((const __attribute__((address_space(1))) void*)(p))
#define LAS(p) ((__attribute__((address_space(3))) void*)(p))

__device__ __forceinline__ void split2(float f, ushort_t& h, ushort_t& l) {
    const unsigned u = __float_as_uint(f);
    h = (ushort_t)(u >> 16);                              // truncate hi
    const float hf = __uint_as_float(u & 0xFFFF0000u);
    l = (ushort_t)(__float_as_uint(f - hf) >> 16);        // truncate residual
}

// ---------------------------------------------------------------- prep kernels
// fused: x-split (16384 blocks) + w1-split (1024 blocks)
__global__ __launch_bounds__(256)
void fused_split(const float* __restrict__ x, ushort_t* __restrict__ xh, ushort_t* __restrict__ xl,
                 const float* __restrict__ w1, ushort_t* __restrict__ w1h, ushort_t* __restrict__ w1l) {
    const int bid = blockIdx.x;
    const float* src; ushort_t* hi; ushort_t* lo; int i;
    if (bid < 16384) { src = x;  hi = xh;  lo = xl;  i = bid * 256 + threadIdx.x; }
    else             { src = w1; hi = w1h; lo = w1l; i = (bid - 16384) * 256 + threadIdx.x; }
    const float4 v = ((const float4*)src)[i];
    ushort4 h, l;
    split2(v.x, h.x, l.x); split2(v.y, h.y, l.y);
    split2(v.z, h.z, l.z); split2(v.w, h.w, l.w);
    ((ushort4*)hi)[i] = h;
    ((ushort4*)lo)[i] = l;
}

// split-K fp32 GEMM: Cp[z] partial of C[m][n] = sum_k A[m*K+k]*W[n*K+k]
constexpr int PKT = 16;
__global__ __launch_bounds__(256)
void prep_gemm_sk(const float* __restrict__ A, const float* __restrict__ W,
                  float* __restrict__ Cp, int M, int N, int K, int KS) {
    __shared__ float As[PKT][68];
    __shared__ float Bs[PKT][68];
    const int tid = threadIdx.x;
    const int bn = blockIdx.x, bm = blockIdx.y, bz = blockIdx.z;
    const int kc = K / KS, k0 = bz * kc;
    const int tx = tid & 15, ty = tid >> 4;
    float acc[4][4];
#pragma unroll
    for (int i = 0; i < 4; ++i)
#pragma unroll
        for (int j = 0; j < 4; ++j) acc[i][j] = 0.f;
    const float* Ab = A + (size_t)(bm * 64) * K + k0;
    const float* Wb = W + (size_t)(bn * 64) * K + k0;
    const int sr = tid >> 2;
    const int sc = (tid & 3) * 4;
    for (int kt = 0; kt < kc; kt += PKT) {
        const float4 va = *(const float4*)(Ab + (size_t)sr * K + kt + sc);
        As[sc + 0][sr] = va.x; As[sc + 1][sr] = va.y; As[sc + 2][sr] = va.z; As[sc + 3][sr] = va.w;
        const float4 vb = *(const float4*)(Wb + (size_t)sr * K + kt + sc);
        Bs[sc + 0][sr] = vb.x; Bs[sc + 1][sr] = vb.y; Bs[sc + 2][sr] = vb.z; Bs[sc + 3][sr] = vb.w;
        __syncthreads();
#pragma unroll
        for (int k = 0; k < PKT; ++k) {
            const float4 a4 = *(const float4*)&As[k][ty * 4];
            const float4 b4 = *(const float4*)&Bs[k][tx * 4];
            const float a[4] = {a4.x, a4.y, a4.z, a4.w};
            const float b[4] = {b4.x, b4.y, b4.z, b4.w};
#pragma unroll
            for (int i = 0; i < 4; ++i)
#pragma unroll
                for (int j = 0; j < 4; ++j) acc[i][j] = fmaf(a[i], b[j], acc[i][j]);
        }
        __syncthreads();
    }
    float* Cb = Cp + (size_t)bz * M * N + (size_t)(bm * 64 + ty * 4) * N + bn * 64 + tx * 4;
#pragma unroll
    for (int i = 0; i < 4; ++i)
        *(float4*)(Cb + (size_t)i * N) = make_float4(acc[i][0], acc[i][1], acc[i][2], acc[i][3]);
}

// fused small prep: combine_split(m2) [256 blocks] + tsplit(cW2) [256] + bias2eff [64]
__global__ __launch_bounds__(256)
void prep_small(const float* __restrict__ m2p, ushort_t* __restrict__ m2h, ushort_t* __restrict__ m2l,
                const float* __restrict__ cW2, ushort_t* __restrict__ cw2h, ushort_t* __restrict__ cw2l,
                const float* __restrict__ cb1, const float* __restrict__ w2,
                const float* __restrict__ b2, float* __restrict__ b2e) {
    const int bid = blockIdx.x;
    if (bid < 256) {                       // combine KS=4 partials of m2, split
        const int i = bid * 256 + threadIdx.x;      // n4 = 65536
        float4 s = ((const float4*)m2p)[i];
#pragma unroll
        for (int z = 1; z < 4; ++z) {
            const float4 v = ((const float4*)m2p)[(size_t)z * 65536 + i];
            s.x += v.x; s.y += v.y; s.z += v.z; s.w += v.w;
        }
        ushort4 h, l;
        split2(s.x, h.x, l.x); split2(s.y, h.y, l.y);
        split2(s.z, h.z, l.z); split2(s.w, h.w, l.w);
        ((ushort4*)m2h)[i] = h;
        ((ushort4*)m2l)[i] = l;
    } else if (bid < 512) {                // transpose-split cW2 [256,256]
        const int i = (bid - 256) * 256 + threadIdx.x;
        const int r = i >> 8, c = i & 255;
        ushort_t h, l;
        split2(cW2[r * 256 + c], h, l);
        cw2h[c * 256 + r] = h;
        cw2l[c * 256 + r] = l;
    } else {                               // bias2eff[n] = dot(cb1, w2[n,:]) + b2[n]
        const int wave = threadIdx.x >> 6, lane = threadIdx.x & 63;
        const int n = (bid - 512) * 4 + wave;
        const float4* row = (const float4*)(w2 + (size_t)n * 1024);
        const float4* c4  = (const float4*)cb1;
        float s = 0.f;
#pragma unroll
        for (int i = 0; i < 4; ++i) {
            const int idx = lane + i * 64;
            const float4 a = row[idx], c = c4[idx];
            s += a.x * c.x + a.y * c.y + a.z * c.z + a.w * c.w;
        }
#pragma unroll
        for (int off = 32; off; off >>= 1) s += __shfl_down(s, off);
        if (lane == 0) b2e[n] = s + b2[n];
    }
}

// ================================================================ G1 kernel
// 256x256 tile, BK=32, 512 thr (8 waves 2Mx4N), wave tile 128x64 (8x4 frags).
// LDS: 2 sets x {Ah,Al,Bh,Bl} x 256rows x 32k bf16 = 128 KB, granule-major:
//   elem(row, g=k>>3, e=k&7) at ushort idx g*2048 + row*8 + e -> 16-lane group
//   ds_read_b128 covers 256B contiguous (conflict-free), gload_lds-linear.
// 2-phase dbuf: stage(next) -> read B once + A in 2 clusters (each read ONCE)
//   -> MFMA -> vmcnt(0) -> ONE barrier per K-tile.
__global__ __launch_bounds__(512, 2)
void kan_mfma256(const ushort_t* __restrict__ Ahg,
                 const ushort_t* __restrict__ Alg,
                 const ushort_t* __restrict__ Bhg,
                 const ushort_t* __restrict__ Blg,
                 const float* __restrict__ bias,
                 const float* __restrict__ coeffs,
                 ushort_t* __restrict__ Chh,
                 ushort_t* __restrict__ Chl,
                 int M, int N, int K)
{
    __shared__ __align__(16) ushort_t LDS[2][4][256 * 32];  // [set][Ah,Al,Bh,Bl]

    const int tid  = threadIdx.x;
    const int lane = tid & 63;
    const int wave = tid >> 6;

    // bijective XCD swizzle (nwg = 256, %8==0)
    const int gx  = gridDim.x;
    const int nwg = gx * gridDim.y;
    int wg = blockIdx.y * gx + blockIdx.x;
    wg = (wg & 7) * (nwg >> 3) + (wg >> 3);
    const int bn = wg % gx;
    const int bm = wg / gx;

    const int wm = wave >> 2;        // 0..1  (M half)
    const int wn = wave & 3;         // 0..3  (N quarter)
    const int lr = lane & 15;
    const int lg = lane >> 4;

    // staging role: wave covers granule sg = wave&3, row chunk (wave>>2)*128
    const int sg  = wave & 3;
    const int r0a = (wave >> 2) * 128;
    const size_t aRow0 = (size_t)bm * 256;
    const size_t bRow0 = (size_t)bn * 256;

    f32x4 acc[8][4];
#pragma unroll
    for (int m = 0; m < 8; ++m)
#pragma unroll
        for (int n = 0; n < 4; ++n) acc[m][n] = f32x4{0.f, 0.f, 0.f, 0.f};

    auto stage = [&](int s, int kt) {
#pragma unroll
        for (int rc = 0; rc < 2; ++rc) {
            const int r0 = r0a + rc * 64;
            const size_t ga = (aRow0 + r0 + lane) * K + kt + sg * 8;
            const size_t gb = (bRow0 + r0 + lane) * K + kt + sg * 8;
            const int di = sg * 2048 + r0 * 8;
            __builtin_amdgcn_global_load_lds(GAS(Ahg + ga), LAS(&LDS[s][0][di]), 16, 0, 0);
            __builtin_amdgcn_global_load_lds(GAS(Alg + ga), LAS(&LDS[s][1][di]), 16, 0, 0);
            __builtin_amdgcn_global_load_lds(GAS(Bhg + gb), LAS(&LDS[s][2][di]), 16, 0, 0);
            __builtin_amdgcn_global_load_lds(GAS(Blg + gb), LAS(&LDS[s][3][di]), 16, 0, 0);
        }
    };

    // prologue: stage tile 0 into set 0
    stage(0, 0);
    asm volatile("s_waitcnt vmcnt(0)" ::: "memory");
    __builtin_amdgcn_s_barrier();

    const int nt = K >> 5;

#define CLUSTER256(MH)                                                          \
    {                                                                           \
        short8 ah[4], al4[4];                                                   \
        _Pragma("unroll")                                                       \
        for (int m = 0; m < 4; ++m) {                                           \
            const int idx = lg * 2048 + (wm * 128 + (MH) * 64 + m * 16 + lr) * 8;\
            ah[m]  = *(const short8*)&LDS[cur][0][idx];                         \
            al4[m] = *(const short8*)&LDS[cur][1][idx];                         \
        }                                                                       \
        asm volatile("s_waitcnt lgkmcnt(0)" ::: "memory");                      \
        __builtin_amdgcn_sched_barrier(0);                                      \
        __builtin_amdgcn_s_setprio(1);                                          \
        _Pragma("unroll")                                                       \
        for (int m = 0; m < 4; ++m)                                             \
            _Pragma("unroll")                                                   \
            for (int n = 0; n < 4; ++n) {                                       \
                acc[(MH)*4+m][n] = __builtin_amdgcn_mfma_f32_16x16x32_bf16(ah[m],  bh[n], acc[(MH)*4+m][n], 0, 0, 0); \
                acc[(MH)*4+m][n] = __builtin_amdgcn_mfma_f32_16x16x32_bf16(ah[m],  bl[n], acc[(MH)*4+m][n], 0, 0, 0); \
                acc[(MH)*4+m][n] = __builtin_amdgcn_mfma_f32_16x16x32_bf16(al4[m], bh[n], acc[(MH)*4+m][n], 0, 0, 0); \
            }                                                                   \
        __builtin_amdgcn_s_setprio(0);                                          \
    }

    for (int t = 0; t < nt; ++t) {
        const int cur = t & 1;
        const bool more = (t + 1) < nt;

        if (more) stage(cur ^ 1, (t + 1) << 5);   // prefetch next K-tile

        // read all B fragments once (kept live across both clusters)
        short8 bh[4], bl[4];
#pragma unroll
        for (int n = 0; n < 4; ++n) {
            const int idx = lg * 2048 + (wn * 64 + n * 16 + lr) * 8;
            bh[n] = *(const short8*)&LDS[cur][2][idx];
            bl[n] = *(const short8*)&LDS[cur][3][idx];
        }
        CLUSTER256(0)
        CLUSTER256(1)

        if (more) {
            asm volatile("s_waitcnt vmcnt(0)" ::: "memory");  // drain next-tile loads (covered by 96 MFMA)
            __builtin_amdgcn_s_barrier();
        }
    }
#undef CLUSTER256

    // ---- epilogue: bias + cheb + split store. C/D: col=lane&15, row=(lane>>4)*4+j
    const int gm0 = bm * 256 + wm * 128;
    const int gn0 = bn * 256 + wn * 64;
#pragma unroll
    for (int n = 0; n < 4; ++n) {
        const int colg = gn0 + n * 16 + lr;
        const float bia = bias[colg];
        float cf[8];
        {
            const float4 u0 = *(const float4*)(coeffs + (size_t)colg * 8);
            const float4 u1 = *(const float4*)(coeffs + (size_t)colg * 8 + 4);
            cf[0] = u0.x; cf[1] = u0.y; cf[2] = u0.z; cf[3] = u0.w;
            cf[4] = u1.x; cf[5] = u1.y; cf[6] = u1.z; cf[7] = u1.w;
        }
#pragma unroll
        for (int m = 0; m < 8; ++m) {
            const int rowb = gm0 + m * 16 + lg * 4;
#pragma unroll
            for (int j = 0; j < 4; ++j) {
                const float alpha = acc[m][n][j] + bia;
                float tm2 = 1.f, tm1 = alpha;
                float v = fmaf(cf[1], alpha, cf[0]);
#pragma unroll
                for (int d = 2; d < 8; ++d) {
                    const float tch = 2.f * alpha * tm1 - tm2;
                    v = fmaf(cf[d], tch, v);
                    tm2 = tm1; tm1 = tch;
                }
                const size_t o = (size_t)(rowb + j) * N + colg;
                ushort_t h, l2;
                split2(v, h, l2);
                Chh[o] = h; Chl[o] = l2;
            }
        }
    }
}

// ================================================================ 128^2 kernel (G3/G4)
// Same 2-phase dbuf schedule; LDS 2 x 32 KB = 64 KB -> 2 blocks/CU.
template<bool CHEB, bool OUT_F32>
__global__ __launch_bounds__(256, 2)
void kan_mfma(const ushort_t* __restrict__ Ahg,
              const ushort_t* __restrict__ Alg,
              const ushort_t* __restrict__ Bhg,
              const ushort_t* __restrict__ Blg,
              const float* __restrict__ bias,
              const float* __restrict__ coeffs,
              float* __restrict__ Cf,
              ushort_t* __restrict__ Chh,
              ushort_t* __restrict__ Chl,
              int M, int N, int K)
{
    __shared__ __align__(16) ushort_t LDS[2][4][128 * 32];  // [set][Ah,Al,Bh,Bl]

    const int tid  = threadIdx.x;
    const int lane = tid & 63;
    const int wave = tid >> 6;

    const int gx = gridDim.x;
    const int nwg = gx * gridDim.y;
    int wg = blockIdx.y * gx + blockIdx.x;
    wg = (wg & 7) * (nwg >> 3) + (wg >> 3);
    const int bn = wg % gx;
    const int bm = wg / gx;

    const int wm = wave >> 1, wn = wave & 1;
    const int lr = lane & 15;
    const int lg = lane >> 4;

    f32x4 acc[4][4];
#pragma unroll
    for (int m = 0; m < 4; ++m)
#pragma unroll
        for (int n = 0; n < 4; ++n) acc[m][n] = f32x4{0.f, 0.f, 0.f, 0.f};

    const size_t aRow0 = (size_t)(bm * 128);
    const size_t bRow0 = (size_t)(bn * 128);
    const int sg = wave;             // granule staged by this wave
    const int ldsb = sg * 1024;

    auto stage = [&](int s, int kt) {
#pragma unroll
        for (int rc = 0; rc < 2; ++rc) {
            const int r0 = rc * 64;
            const size_t ga = (aRow0 + r0 + lane) * K + kt + sg * 8;
            const size_t gb = (bRow0 + r0 + lane) * K + kt + sg * 8;
            const int di = ldsb + r0 * 8;
            __builtin_amdgcn_global_load_lds(GAS(Ahg + ga), LAS(&LDS[s][0][di]), 16, 0, 0);
            __builtin_amdgcn_global_load_lds(GAS(Alg + ga), LAS(&LDS[s][1][di]), 16, 0, 0);
            __builtin_amdgcn_global_load_lds(GAS(Bhg + gb), LAS(&LDS[s][2][di]), 16, 0, 0);
            __builtin_amdgcn_global_load_lds(GAS(Blg + gb), LAS(&LDS[s][3][di]), 16, 0, 0);
        }
    };

    stage(0, 0);
    asm volatile("s_waitcnt vmcnt(0)" ::: "memory");
    __builtin_amdgcn_s_barrier();

    const int nt = K >> 5;
    for (int t = 0; t < nt; ++t) {
        const int cur = t & 1;
        const bool more = (t + 1) < nt;

        if (more) stage(cur ^ 1, (t + 1) << 5);

        short8 a_h[4], a_l[4], b_h[4], b_l[4];
#pragma unroll
        for (int m = 0; m < 4; ++m) {
            const int off = lg * 1024 + (wm * 64 + m * 16 + lr) * 8;
            a_h[m] = *(const short8*)&LDS[cur][0][off];
            a_l[m] = *(const short8*)&LDS[cur][1][off];
        }
#pragma unroll
        for (int n = 0; n < 4; ++n) {
            const int off = lg * 1024 + (wn * 64 + n * 16 + lr) * 8;
            b_h[n] = *(const short8*)&LDS[cur][2][off];
            b_l[n] = *(const short8*)&LDS[cur][3][off];
        }
        asm volatile("s_waitcnt lgkmcnt(0)" ::: "memory");
        __builtin_amdgcn_sched_barrier(0);
        __builtin_amdgcn_s_setprio(1);
#pragma unroll
        for (int m = 0; m < 4; ++m)
#pragma unroll
            for (int n = 0; n < 4; ++n) {
                acc[m][n] = __builtin_amdgcn_mfma_f32_16x16x32_bf16(a_h[m], b_h[n], acc[m][n], 0, 0, 0);
                acc[m][n] = __builtin_amdgcn_mfma_f32_16x16x32_bf16(a_h[m], b_l[n], acc[m][n], 0, 0, 0);
                acc[m][n] = __builtin_amdgcn_mfma_f32_16x16x32_bf16(a_l[m], b_h[n], acc[m][n], 0, 0, 0);
            }
        __builtin_amdgcn_s_setprio(0);

        if (more) {
            asm volatile("s_waitcnt vmcnt(0)" ::: "memory");
            __builtin_amdgcn_s_barrier();
        }
    }

    const int gm0 = bm * 128 + wm * 64;
    const int gn0 = bn * 128 + wn * 64;
#pragma unroll
    for (int n = 0; n < 4; ++n) {
        const int colg = gn0 + n * 16 + lr;
        const float bia = bias[colg];
        float cf[8];
        if constexpr (CHEB) {
            const float4 u0 = *(const float4*)(coeffs + (size_t)colg * 8);
            const float4 u1 = *(const float4*)(coeffs + (size_t)colg * 8 + 4);
            cf[0] = u0.x; cf[1] = u0.y; cf[2] = u0.z; cf[3] = u0.w;
            cf[4] = u1.x; cf[5] = u1.y; cf[6] = u1.z; cf[7] = u1.w;
        }
#pragma unroll
        for (int m = 0; m < 4; ++m) {
            const int rowb = gm0 + m * 16 + lg * 4;
#pragma unroll
            for (int j = 0; j < 4; ++j) {
                const float alpha = acc[m][n][j] + bia;
                float v;
                if constexpr (CHEB) {
                    float tm2 = 1.f, tm1 = alpha;
                    v = fmaf(cf[1], alpha, cf[0]);
#pragma unroll
                    for (int d = 2; d < 8; ++d) {
                        const float t2 = 2.f * alpha * tm1 - tm2;
                        v = fmaf(cf[d], t2, v);
                        tm2 = tm1; tm1 = t2;
                    }
                } else {
                    v = alpha;
                }
                const size_t o = (size_t)(rowb + j) * N + colg;
                if constexpr (OUT_F32) {
                    Cf[o] = v;
                } else {
                    ushort_t h, l2;
                    split2(v, h, l2);
                    Chh[o] = h; Chl[o] = l2;
                }
            }
        }
    }
}

// ---------------------------------------------------------------- launch
extern "C" void kernel_launch(void* const* d_in, const int* in_sizes, int n_in,
                              void* d_out, int out_size, void* d_ws, size_t ws_size,
                              hipStream_t stream) {
    const float* x       = (const float*)d_in[0];
    const float* w1      = (const float*)d_in[1];
    const float* b1      = (const float*)d_in[2];
    const float* coeffs1 = (const float*)d_in[3];
    const float* cW1     = (const float*)d_in[4];
    const float* cb1     = (const float*)d_in[5];
    const float* w2      = (const float*)d_in[6];
    const float* b2      = (const float*)d_in[7];
    const float* coeffs2 = (const float*)d_in[8];
    const float* cW2     = (const float*)d_in[9];
    const float* cb2     = (const float*)d_in[10];

    constexpr int B  = 16384;
    constexpr int D1 = 1024;
    constexpr int D2 = 256;
    constexpr int KS = 4;

    char* w = (char*)d_ws;
    size_t off = 0;
    auto alloc = [&](size_t bytes) { char* p = w + off; off += (bytes + 255) & ~(size_t)255; return p; };
    ushort_t* xh   = (ushort_t*)alloc((size_t)B * D1 * 2);
    ushort_t* xl   = (ushort_t*)alloc((size_t)B * D1 * 2);
    ushort_t* hh   = (ushort_t*)alloc((size_t)B * D1 * 2);
    ushort_t* hl   = (ushort_t*)alloc((size_t)B * D1 * 2);
    ushort_t* ph   = (ushort_t*)alloc((size_t)B * D2 * 2);
    ushort_t* pl   = (ushort_t*)alloc((size_t)B * D2 * 2);
    ushort_t* w1h  = (ushort_t*)alloc((size_t)D1 * D1 * 2);
    ushort_t* w1l  = (ushort_t*)alloc((size_t)D1 * D1 * 2);
    float*    m2p  = (float*)alloc((size_t)KS * D2 * D1 * 4);
    ushort_t* m2h  = (ushort_t*)alloc((size_t)D2 * D1 * 2);
    ushort_t* m2l  = (ushort_t*)alloc((size_t)D2 * D1 * 2);
    ushort_t* cw2h = (ushort_t*)alloc((size_t)D2 * D2 * 2);
    ushort_t* cw2l = (ushort_t*)alloc((size_t)D2 * D2 * 2);
    float*    b2e  = (float*)alloc(D2 * 4);

    // ---- prep (3 launches)
    fused_split<<<dim3(B * D1 / 4 / 256 + D1 * D1 / 4 / 256), dim3(256), 0, stream>>>(
        x, xh, xl, w1, w1h, w1l);
    prep_gemm_sk<<<dim3(D1 / 64, D2 / 64, KS), dim3(256), 0, stream>>>(w2, cW1, m2p, D2, D1, D1, KS);
    prep_small<<<dim3(576), dim3(256), 0, stream>>>(m2p, m2h, m2l, cW2, cw2h, cw2l, cb1, w2, b2, b2e);

    // ---- main pipeline
    // G1: n1 = cheb1(x @ w1^T + b1) -> hh/hl   (256^2 2-phase dbuf)
    kan_mfma256<<<dim3(D1 / 256, B / 256), dim3(512), 0, stream>>>(
        xh, xl, w1h, w1l, b1, coeffs1, hh, hl, B, D1, D1);
    // G3: p = cheb2(n1 @ M2T^T + bias2eff) -> ph/pl
    kan_mfma<true, false><<<dim3(D2 / 128, B / 128), dim3(256), 0, stream>>>(
        hh, hl, m2h, m2l, b2e, coeffs2, nullptr, ph, pl, B, D2, D1);
    // G4: out = p @ cW2 + cb2 -> d_out (f32)
    kan_mfma<false, true><<<dim3(D2 / 128, B / 128), dim3(256), 0, stream>>>(
        ph, pl, cw2h, cw2l, cb2, nullptr, (float*)d_out, nullptr, nullptr, B, D2, D2);
}